// Round 1
// baseline (260.777 us; speedup 1.0000x reference)
//
#include <hip/hip_runtime.h>

// CenterLoss on MI355X.
// B=16384 samples, F=256 features, C=100000 classes, DECAY=0.99.
// loss = mean_{i,f} (x[i,f] - (0.99*center[l_i,f] + 0.01*mean_class[l_i,f]))^2
// Only classes present in the batch are gathered -> the `present` predicate in
// the reference never matters for the loss value.

#define NUM_CLASSES 100000
#define FEAT 256
#define BATCH 16384
#define DECAYF 0.99f
#define ONE_MINUS_DECAYF 0.01f

// ws layout (floats):
//   [0, C)           counts
//   [C]              loss accumulator
//   [C+4, C+4+C*F)   sums  (C==100000 divisible by 4 -> 16B aligned)
static constexpr size_t WS_COUNTS = 0;
static constexpr size_t WS_ACC    = NUM_CLASSES;
static constexpr size_t WS_SUMS   = NUM_CLASSES + 4;

// Each block: 256 threads = 4 waves-worth of work slots; each group of 64
// threads handles one sample's 256-float row via float4 (64 lanes x 16B).

__global__ __launch_bounds__(256) void zero_rows_and_count(
    const int* __restrict__ label, float* __restrict__ counts,
    float* __restrict__ sums) {
  int s = blockIdx.x * 4 + (threadIdx.x >> 6);
  int t = threadIdx.x & 63;
  int l = label[s];
  float4 z = make_float4(0.f, 0.f, 0.f, 0.f);
  reinterpret_cast<float4*>(sums + (size_t)l * FEAT)[t] = z;  // dup labels: benign same-value race
  if (t == 0) atomicAdd(&counts[l], 1.0f);
}

__global__ __launch_bounds__(256) void scatter_sums(
    const float* __restrict__ x, const int* __restrict__ label,
    float* __restrict__ sums) {
  int s = blockIdx.x * 4 + (threadIdx.x >> 6);
  int t = threadIdx.x & 63;
  int l = label[s];
  float4 v = reinterpret_cast<const float4*>(x + (size_t)s * FEAT)[t];
  float* row = sums + (size_t)l * FEAT + t * 4;
  atomicAdd(row + 0, v.x);
  atomicAdd(row + 1, v.y);
  atomicAdd(row + 2, v.z);
  atomicAdd(row + 3, v.w);
}

__global__ __launch_bounds__(256) void loss_kernel(
    const float* __restrict__ x, const int* __restrict__ label,
    const float* __restrict__ centers, const float* __restrict__ sums,
    const float* __restrict__ counts, float* __restrict__ acc) {
  int s = blockIdx.x * 4 + (threadIdx.x >> 6);
  int t = threadIdx.x & 63;
  int l = label[s];
  float inv_n = 1.0f / counts[l];  // count >= 1 for every gathered class
  float4 xv = reinterpret_cast<const float4*>(x + (size_t)s * FEAT)[t];
  float4 sv = reinterpret_cast<const float4*>(sums + (size_t)l * FEAT)[t];
  float4 cv = reinterpret_cast<const float4*>(centers + (size_t)l * FEAT)[t];
  float w = ONE_MINUS_DECAYF * inv_n;
  float dx = xv.x - (DECAYF * cv.x + w * sv.x);
  float dy = xv.y - (DECAYF * cv.y + w * sv.y);
  float dz = xv.z - (DECAYF * cv.z + w * sv.z);
  float dw = xv.w - (DECAYF * cv.w + w * sv.w);
  float p = dx * dx + dy * dy + dz * dz + dw * dw;

  // wave64 reduce
  #pragma unroll
  for (int off = 32; off > 0; off >>= 1) p += __shfl_down(p, off, 64);
  __shared__ float wsum[4];
  if (t == 0) wsum[threadIdx.x >> 6] = p;
  __syncthreads();
  if (threadIdx.x == 0) atomicAdd(acc, wsum[0] + wsum[1] + wsum[2] + wsum[3]);
}

__global__ void finalize(const float* __restrict__ acc, float* __restrict__ out) {
  out[0] = acc[0] * (1.0f / (float)((size_t)BATCH * FEAT));  // * 2^-22
}

extern "C" void kernel_launch(void* const* d_in, const int* in_sizes, int n_in,
                              void* d_out, int out_size, void* d_ws, size_t ws_size,
                              hipStream_t stream) {
  const float* x = (const float*)d_in[0];
  const int* label = (const int*)d_in[1];
  const float* centers = (const float*)d_in[2];
  float* ws = (float*)d_ws;
  float* counts = ws + WS_COUNTS;
  float* acc = ws + WS_ACC;
  float* sums = ws + WS_SUMS;
  float* out = (float*)d_out;

  // zero counts + accumulator (ws is poisoned 0xAA before every call)
  hipMemsetAsync(counts, 0, (NUM_CLASSES + 4) * sizeof(float), stream);

  dim3 block(256);
  dim3 grid(BATCH / 4);  // 4096 blocks, one sample per 64-thread group
  zero_rows_and_count<<<grid, block, 0, stream>>>(label, counts, sums);
  scatter_sums<<<grid, block, 0, stream>>>(x, label, sums);
  loss_kernel<<<grid, block, 0, stream>>>(x, label, centers, sums, counts, acc);
  finalize<<<1, 1, 0, stream>>>(acc, out);
}

// Round 2
// 209.087 us; speedup vs baseline: 1.2472x; 1.2472x over previous
//
#include <hip/hip_runtime.h>

// CenterLoss on MI355X — round 2.
// Insight: labels are ~92% unique (B=16K, C=100K). For a class with count==1,
// mean == x_i, so diff = 0.99*(x_i - c_l): no sums table needed. Only classes
// with count >= 2 (~1.3K classes, ~2.7K samples) need zero+scatter+gather of
// their sums row. This removes ~98% of the float atomics that dominated R1
// (scatter_sums was 65us, VALUBusy 0.5%, 69MB atomic write traffic).

#define NUM_CLASSES 100000
#define FEAT 256
#define BATCH 16384
#define DECAYF 0.99f

// ws layout (floats):
//   [0, C)           counts
//   [C]              loss accumulator
//   [C+4, C+4+C*F)   sums
static constexpr size_t WS_COUNTS = 0;
static constexpr size_t WS_ACC    = NUM_CLASSES;
static constexpr size_t WS_SUMS   = NUM_CLASSES + 4;

__global__ __launch_bounds__(256) void count_kernel(
    const int* __restrict__ label, float* __restrict__ counts) {
  int s = blockIdx.x * 256 + threadIdx.x;
  atomicAdd(&counts[label[s]], 1.0f);
}

// One sample per 64-lane group; 4 samples per 256-thread block.
__global__ __launch_bounds__(256) void zero_dup_rows(
    const int* __restrict__ label, const float* __restrict__ counts,
    float* __restrict__ sums) {
  int s = blockIdx.x * 4 + (threadIdx.x >> 6);
  int t = threadIdx.x & 63;
  int l = label[s];
  if (counts[l] > 1.5f) {
    float4 z = make_float4(0.f, 0.f, 0.f, 0.f);
    reinterpret_cast<float4*>(sums + (size_t)l * FEAT)[t] = z;  // dup stores benign
  }
}

__global__ __launch_bounds__(256) void scatter_dup(
    const float* __restrict__ x, const int* __restrict__ label,
    const float* __restrict__ counts, float* __restrict__ sums) {
  int s = blockIdx.x * 4 + (threadIdx.x >> 6);
  int t = threadIdx.x & 63;
  int l = label[s];
  if (counts[l] > 1.5f) {
    float4 v = reinterpret_cast<const float4*>(x + (size_t)s * FEAT)[t];
    float* row = sums + (size_t)l * FEAT + t * 4;
    atomicAdd(row + 0, v.x);
    atomicAdd(row + 1, v.y);
    atomicAdd(row + 2, v.z);
    atomicAdd(row + 3, v.w);
  }
}

__global__ __launch_bounds__(256) void loss_kernel(
    const float* __restrict__ x, const int* __restrict__ label,
    const float* __restrict__ centers, const float* __restrict__ sums,
    const float* __restrict__ counts, float* __restrict__ acc) {
  int s = blockIdx.x * 4 + (threadIdx.x >> 6);
  int t = threadIdx.x & 63;
  int l = label[s];
  float n = counts[l];
  float4 xv = reinterpret_cast<const float4*>(x + (size_t)s * FEAT)[t];
  float4 cv = reinterpret_cast<const float4*>(centers + (size_t)l * FEAT)[t];
  float p;
  if (n < 1.5f) {
    // unique class: mean == x, diff = 0.99*(x - c)
    float dx = xv.x - cv.x, dy = xv.y - cv.y, dz = xv.z - cv.z, dw = xv.w - cv.w;
    p = (DECAYF * DECAYF) * (dx * dx + dy * dy + dz * dz + dw * dw);
  } else {
    float4 sv = reinterpret_cast<const float4*>(sums + (size_t)l * FEAT)[t];
    float w = 0.01f / n;
    float dx = xv.x - (DECAYF * cv.x + w * sv.x);
    float dy = xv.y - (DECAYF * cv.y + w * sv.y);
    float dz = xv.z - (DECAYF * cv.z + w * sv.z);
    float dw = xv.w - (DECAYF * cv.w + w * sv.w);
    p = dx * dx + dy * dy + dz * dz + dw * dw;
  }

  #pragma unroll
  for (int off = 32; off > 0; off >>= 1) p += __shfl_down(p, off, 64);
  __shared__ float wsum[4];
  if (t == 0) wsum[threadIdx.x >> 6] = p;
  __syncthreads();
  if (threadIdx.x == 0) atomicAdd(acc, wsum[0] + wsum[1] + wsum[2] + wsum[3]);
}

__global__ void finalize(const float* __restrict__ acc, float* __restrict__ out) {
  out[0] = acc[0] * (1.0f / (float)((size_t)BATCH * FEAT));  // * 2^-22
}

extern "C" void kernel_launch(void* const* d_in, const int* in_sizes, int n_in,
                              void* d_out, int out_size, void* d_ws, size_t ws_size,
                              hipStream_t stream) {
  const float* x = (const float*)d_in[0];
  const int* label = (const int*)d_in[1];
  const float* centers = (const float*)d_in[2];
  float* ws = (float*)d_ws;
  float* counts = ws + WS_COUNTS;
  float* acc = ws + WS_ACC;
  float* sums = ws + WS_SUMS;
  float* out = (float*)d_out;

  hipMemsetAsync(counts, 0, (NUM_CLASSES + 4) * sizeof(float), stream);

  dim3 block(256);
  count_kernel<<<dim3(BATCH / 256), block, 0, stream>>>(label, counts);
  dim3 grid(BATCH / 4);
  zero_dup_rows<<<grid, block, 0, stream>>>(label, counts, sums);
  scatter_dup<<<grid, block, 0, stream>>>(x, label, counts, sums);
  loss_kernel<<<grid, block, 0, stream>>>(x, label, centers, sums, counts, acc);
  finalize<<<1, 1, 0, stream>>>(acc, out);
}